// Round 7
// baseline (561.686 us; speedup 1.0000x reference)
//
#include <hip/hip_runtime.h>
#include <hip/hip_bf16.h>

#define N_NODES 50000
#define N_EDGES 800000
#define NFEAT   512
#define NHID    64
#define NHEADS  8
#define NCLASS  40
#define HD      (NHEADS*NHID)   // 512
#define ALPHA   0.2f
#define EPS_F   1e-16f
#define NCHUNK  ((N_NODES + 255)/256)   // 196

typedef __attribute__((ext_vector_type(8))) short short8;
typedef __attribute__((ext_vector_type(4))) float floatx4;

__device__ __forceinline__ float bf2f(unsigned short u) {
    union { unsigned int i; float f; } v; v.i = ((unsigned int)u) << 16; return v.f;
}
__device__ __forceinline__ unsigned short f2bf(float f) {
    union { __hip_bfloat16 h; unsigned short u; } cv;
    cv.h = __float2bfloat16(f);
    return cv.u;
}

// ---------------------------------------------------------------------------
// Repack W_heads -> Wrb[n][k] bf16 (B^T). Also zero-inits deg (fused).
__global__ void repackWb(const float* __restrict__ Wh, unsigned short* __restrict__ Wrb,
                         int* __restrict__ deg) {
    int idx = blockIdx.x*256 + threadIdx.x;      // n*512 + k
    if (idx < N_NODES) deg[idx] = 0;
    if (idx >= 512*512) return;
    int n = idx >> 9, k = idx & 511;
    int hd = n >> 6, d = n & 63;
    Wrb[idx] = f2bf(Wh[(size_t)hd*NFEAT*NHID + (size_t)k*NHID + d]);
}

// Repack W_out [512][40] -> Woutb[n][k] bf16 (n padded to 64, zeros beyond 40)
__global__ void repackWout(const float* __restrict__ Wo, unsigned short* __restrict__ Wob) {
    int idx = blockIdx.x*256 + threadIdx.x;      // n*512 + k, n < 64
    if (idx >= 64*512) return;
    int n = idx >> 9, k = idx & 511;
    float v = (n < NCLASS) ? Wo[(size_t)k*NCLASS + n] : 0.f;
    Wob[idx] = f2bf(v);
}

// ---------------------------------------------------------------------------
// Layer-1 MFMA GEMM: one block owns a FULL 128-row x 512-col stripe.
// A (fp32) is read from HBM exactly once; B (512 KB) is L2-resident.
// Each permuted output row is written entirely by this block (write merge
// happens in this CU's XCD L2 — no cross-block interleave).
// 512 threads = 8 waves in 2(m) x 4(n); wave tile 64x128 (4x8 MFMA tiles).
// Output permuted: H1p[row*512 + d*8 + hd], col c = hd*64+d.
__global__ __launch_bounds__(512, 2) void mfma_gemm1(const float* __restrict__ A,
                                                     const unsigned short* __restrict__ Bbf,
                                                     unsigned short* __restrict__ H1p, int M) {
    __shared__ short Asl[128*40];    // [m][k] 128x32, pad 40
    __shared__ short Bsl[512*40];    // [n][k] 512x32, pad 40
    int tid  = threadIdx.x;
    int wid  = tid >> 6, lane = tid & 63;
    int lrow = lane & 15, quad = lane >> 4;
    int wm = wid & 1, wn = wid >> 1;     // wm in [0,2), wn in [0,4)
    int row0 = blockIdx.x * 128;
    if (row0 >= M) return;

    floatx4 acc[4][8];
#pragma unroll
    for (int mm = 0; mm < 4; mm++)
#pragma unroll
        for (int nn = 0; nn < 8; nn++) acc[mm][nn] = (floatx4){0.f,0.f,0.f,0.f};

    for (int k0 = 0; k0 < 512; k0 += 32) {
        // A: 128 rows x 4 chunks = 512 chunks; thread t stages chunk t.
        {
            int r = tid >> 2, kk = (tid & 3) * 8;
            int ar = row0 + r; ar = ar < M ? ar : M - 1;
            const float* src = A + (size_t)ar*512 + k0 + kk;
            float4 f0 = *(const float4*)src;
            float4 f1 = *(const float4*)(src + 4);
            short8 h;
            h[0] = (short)f2bf(f0.x); h[1] = (short)f2bf(f0.y);
            h[2] = (short)f2bf(f0.z); h[3] = (short)f2bf(f0.w);
            h[4] = (short)f2bf(f1.x); h[5] = (short)f2bf(f1.y);
            h[6] = (short)f2bf(f1.z); h[7] = (short)f2bf(f1.w);
            *(short8*)(&Asl[r*40 + kk]) = h;
        }
        // B: 512 rows x 4 chunks = 2048 chunks; 4 per thread.
#pragma unroll
        for (int it = 0; it < 4; ++it) {
            int q = tid + it*512;
            int r = q >> 2, kk = (q & 3) * 8;
            *(short8*)(&Bsl[r*40 + kk]) =
                *(const short8*)(Bbf + (size_t)r*512 + k0 + kk);
        }
        __syncthreads();
        short8 af[4], bfr[8];
#pragma unroll
        for (int mm = 0; mm < 4; ++mm)
            af[mm] = *(const short8*)(&Asl[(wm*64 + mm*16 + lrow)*40 + quad*8]);
#pragma unroll
        for (int nn = 0; nn < 8; ++nn)
            bfr[nn] = *(const short8*)(&Bsl[(wn*128 + nn*16 + lrow)*40 + quad*8]);
#pragma unroll
        for (int mm = 0; mm < 4; ++mm)
#pragma unroll
            for (int nn = 0; nn < 8; ++nn)
                acc[mm][nn] = __builtin_amdgcn_mfma_f32_16x16x32_bf16(
                    af[mm], bfr[nn], acc[mm][nn], 0, 0, 0);
        __syncthreads();
    }

#pragma unroll
    for (int mm = 0; mm < 4; ++mm) {
        int rbase = row0 + wm*64 + mm*16 + quad*4;
#pragma unroll
        for (int nn = 0; nn < 8; ++nn) {
            int c = wn*128 + nn*16 + lrow;
            int off = (c & 63)*8 + (c >> 6);     // permuted layout
#pragma unroll
            for (int r = 0; r < 4; ++r) {
                int grow = rbase + r;
                if (grow < M)
                    H1p[(size_t)grow*512 + off] = f2bf(acc[mm][nn][r]);
            }
        }
    }
}

// ---------------------------------------------------------------------------
// Layer-2 MFMA GEMM: H2p[M,64] = hcatb[M,512] @ Woutb^T (cols 40..63 are zero).
__global__ __launch_bounds__(256) void mfma_gemm2(const unsigned short* __restrict__ Abf,
                                                  const unsigned short* __restrict__ Bbf,
                                                  float* __restrict__ H2p, int M) {
    __shared__ short Asl[256*40];
    __shared__ short Bsl[64*40];
    int tid  = threadIdx.x;
    int wid  = tid >> 6, lane = tid & 63;
    int lrow = lane & 15, quad = lane >> 4;
    int row0 = blockIdx.x * 256;

    floatx4 acc[4][4];
#pragma unroll
    for (int mm = 0; mm < 4; mm++)
#pragma unroll
        for (int nn = 0; nn < 4; nn++) acc[mm][nn] = (floatx4){0.f,0.f,0.f,0.f};

    for (int k0 = 0; k0 < 512; k0 += 32) {
#pragma unroll
        for (int it = 0; it < 4; ++it) {     // A: 256 rows x 32k = 1024 chunks
            int q  = tid + it*256;
            int r  = q >> 2, kk = (q & 3) * 8;
            int ar = row0 + r; ar = ar < M ? ar : M - 1;
            *(short8*)(&Asl[r*40 + kk]) =
                *(const short8*)(Abf + (size_t)ar*512 + k0 + kk);
        }
        {                                    // B: 64 rows x 32k = 256 chunks
            int r = tid >> 2, kk = (tid & 3) * 8;
            *(short8*)(&Bsl[r*40 + kk]) =
                *(const short8*)(Bbf + (size_t)r*512 + k0 + kk);
        }
        __syncthreads();
        short8 af[4], bfr[4];
#pragma unroll
        for (int mm = 0; mm < 4; ++mm)
            af[mm] = *(const short8*)(&Asl[(wid*64 + mm*16 + lrow)*40 + quad*8]);
#pragma unroll
        for (int nn = 0; nn < 4; ++nn)
            bfr[nn] = *(const short8*)(&Bsl[(nn*16 + lrow)*40 + quad*8]);
#pragma unroll
        for (int mm = 0; mm < 4; ++mm)
#pragma unroll
            for (int nn = 0; nn < 4; ++nn)
                acc[mm][nn] = __builtin_amdgcn_mfma_f32_16x16x32_bf16(
                    af[mm], bfr[nn], acc[mm][nn], 0, 0, 0);
        __syncthreads();
    }

#pragma unroll
    for (int mm = 0; mm < 4; ++mm) {
        int rbase = row0 + wid*64 + mm*16 + quad*4;
#pragma unroll
        for (int nn = 0; nn < 4; ++nn) {
            int c = nn*16 + lrow;
#pragma unroll
            for (int r = 0; r < 4; ++r) {
                int grow = rbase + r;
                if (grow < M)
                    H2p[(size_t)grow*64 + c] = acc[mm][nn][r];
            }
        }
    }
}

// ---------------------------------------------------------------------------
// Attention dots from PERMUTED H1p. One wave per node; lane = feature d.
__global__ __launch_bounds__(256) void dots1(const unsigned short* __restrict__ H1p,
                                             const float* __restrict__ a_heads,
                                             float* __restrict__ srcdot,
                                             float* __restrict__ dstdot) {
    int wave = (blockIdx.x*256 + threadIdx.x) >> 6;
    int lane = threadIdx.x & 63;
    if (wave >= N_NODES) return;
    short8 hv = *(const short8*)(H1p + (size_t)wave*512 + lane*8);
    float s0[8], s1[8];
#pragma unroll
    for (int j = 0; j < 8; j++) {
        float h = bf2f((unsigned short)hv[j]);
        s0[j] = h * a_heads[j*128 + lane];
        s1[j] = h * a_heads[j*128 + 64 + lane];
    }
#pragma unroll
    for (int off = 32; off > 0; off >>= 1) {
#pragma unroll
        for (int j = 0; j < 8; j++) {
            s0[j] += __shfl_down(s0[j], off, 64);
            s1[j] += __shfl_down(s1[j], off, 64);
        }
    }
    if (lane == 0) {
#pragma unroll
        for (int j = 0; j < 8; j++) {
            srcdot[wave*8 + j] = s0[j];
            dstdot[wave*8 + j] = s1[j];
        }
    }
}

// ---------------------------------------------------------------------------
// CSR build
__global__ void histk(const int* __restrict__ row, int* __restrict__ deg) {
    int e = blockIdx.x*256 + threadIdx.x;
    if (e < N_EDGES) atomicAdd(&deg[row[e]], 1);
}
__global__ void scanA(const int* __restrict__ deg, int* __restrict__ row_ptr,
                      int* __restrict__ chunk_tot) {
    __shared__ int s[256];
    int t = threadIdx.x;
    int idx = blockIdx.x*256 + t;
    int v = (idx < N_NODES) ? deg[idx] : 0;
    s[t] = v;
    __syncthreads();
#pragma unroll
    for (int off = 1; off < 256; off <<= 1) {
        int x = (t >= off) ? s[t-off] : 0;
        __syncthreads();
        s[t] += x;
        __syncthreads();
    }
    if (idx < N_NODES) row_ptr[idx] = s[t] - v;
    if (t == 255) chunk_tot[blockIdx.x] = s[t];
}
__global__ void scanB(const int* __restrict__ chunk_tot, int* __restrict__ chunk_off,
                      int* __restrict__ row_ptr) {
    __shared__ int s[256];
    int t = threadIdx.x;
    int v = (t < NCHUNK) ? chunk_tot[t] : 0;
    s[t] = v;
    __syncthreads();
#pragma unroll
    for (int off = 1; off < 256; off <<= 1) {
        int x = (t >= off) ? s[t-off] : 0;
        __syncthreads();
        s[t] += x;
        __syncthreads();
    }
    if (t < NCHUNK) chunk_off[t] = s[t] - v;
    if (t == 255) row_ptr[N_NODES] = s[t];
}
__global__ void scanC(const int* __restrict__ chunk_off, int* __restrict__ row_ptr,
                      int* __restrict__ cursor) {
    int idx = blockIdx.x*256 + threadIdx.x;
    if (idx < N_NODES) {
        int rp = row_ptr[idx] + chunk_off[idx >> 8];
        row_ptr[idx] = rp;
        cursor[idx] = rp;
    }
}

// Fused CSR fill + layer-1 edge weights, stored in CSR slot order.
__global__ void fillk_w1(const int* __restrict__ row, const int* __restrict__ col,
                         const float* __restrict__ srcdot, const float* __restrict__ dstdot,
                         int* __restrict__ cursor, int* __restrict__ csr_col,
                         float* __restrict__ Wcsr) {
    int e = blockIdx.x*256 + threadIdx.x;
    if (e >= N_EDGES) return;
    int r = row[e], c = col[e];
    int pos = atomicAdd(&cursor[r], 1);
    csr_col[pos] = c;
    float4 sa = *(const float4*)(srcdot + (size_t)r*8);
    float4 sb = *(const float4*)(srcdot + (size_t)r*8 + 4);
    float4 da = *(const float4*)(dstdot + (size_t)c*8);
    float4 db = *(const float4*)(dstdot + (size_t)c*8 + 4);
    float s[8] = {sa.x+da.x, sa.y+da.y, sa.z+da.z, sa.w+da.w,
                  sb.x+db.x, sb.y+db.y, sb.z+db.z, sb.w+db.w};
    float o[8];
#pragma unroll
    for (int j = 0; j < 8; j++) {
        float lr = s[j] > 0.f ? s[j] : ALPHA*s[j];
        o[j] = __expf(-lr);
    }
    *(float4*)(Wcsr + (size_t)pos*8)     = make_float4(o[0], o[1], o[2], o[3]);
    *(float4*)(Wcsr + (size_t)pos*8 + 4) = make_float4(o[4], o[5], o[6], o[7]);
}

// ---------------------------------------------------------------------------
// Layer-1 aggregation + ELU. Wave per node; ONE 16-B gather per edge per lane;
// 4-edge unroll keeps 4 gathers in flight.
__global__ __launch_bounds__(256) void agg1(const unsigned short* __restrict__ H1p,
                                            const float* __restrict__ Wcsr,
                                            const int* __restrict__ row_ptr,
                                            const int* __restrict__ csr_col,
                                            unsigned short* __restrict__ hcatb) {
    int wave = (blockIdx.x*256 + threadIdx.x) >> 6;
    int lane = threadIdx.x & 63;
    if (wave >= N_NODES) return;
    int start = row_ptr[wave], end = row_ptr[wave+1];
    float acc[8], den[8];
#pragma unroll
    for (int j = 0; j < 8; j++) { acc[j] = 0.f; den[j] = 0.f; }

    int k = start;
    for (; k + 4 <= end; k += 4) {
        int c0 = csr_col[k],   c1 = csr_col[k+1];
        int c2 = csr_col[k+2], c3 = csr_col[k+3];
        short8 hv0 = *(const short8*)(H1p + (size_t)c0*512 + lane*8);
        short8 hv1 = *(const short8*)(H1p + (size_t)c1*512 + lane*8);
        short8 hv2 = *(const short8*)(H1p + (size_t)c2*512 + lane*8);
        short8 hv3 = *(const short8*)(H1p + (size_t)c3*512 + lane*8);
        float4 wv[8];
#pragma unroll
        for (int q = 0; q < 8; q++)
            wv[q] = *(const float4*)(Wcsr + (size_t)k*8 + q*4);
        const float* w0 = (const float*)&wv[0];
        const float* w1 = (const float*)&wv[2];
        const float* w2 = (const float*)&wv[4];
        const float* w3 = (const float*)&wv[6];
#pragma unroll
        for (int j = 0; j < 8; j++) {
            den[j] += (w0[j] + w1[j]) + (w2[j] + w3[j]);
            acc[j] = fmaf(w0[j], bf2f((unsigned short)hv0[j]), acc[j]);
            acc[j] = fmaf(w1[j], bf2f((unsigned short)hv1[j]), acc[j]);
            acc[j] = fmaf(w2[j], bf2f((unsigned short)hv2[j]), acc[j]);
            acc[j] = fmaf(w3[j], bf2f((unsigned short)hv3[j]), acc[j]);
        }
    }
    for (; k < end; ++k) {
        int c = csr_col[k];
        float4 wa = *(const float4*)(Wcsr + (size_t)k*8);
        float4 wb = *(const float4*)(Wcsr + (size_t)k*8 + 4);
        short8 hv = *(const short8*)(H1p + (size_t)c*512 + lane*8);
        float w[8] = {wa.x, wa.y, wa.z, wa.w, wb.x, wb.y, wb.z, wb.w};
#pragma unroll
        for (int j = 0; j < 8; j++) {
            den[j] += w[j];
            acc[j] = fmaf(w[j], bf2f((unsigned short)hv[j]), acc[j]);
        }
    }
#pragma unroll
    for (int j = 0; j < 8; j++) {
        float o = acc[j] / (den[j] + EPS_F);
        o = o > 0.f ? o : (__expf(o) - 1.f);   // ELU
        hcatb[(size_t)wave*HD + j*64 + lane] = f2bf(o);
    }
}

// ---------------------------------------------------------------------------
__global__ void dots2(const float* __restrict__ H2p, const float* __restrict__ a_out,
                      float* __restrict__ src2, float* __restrict__ dst2) {
    int i = blockIdx.x*256 + threadIdx.x;
    if (i >= N_NODES) return;
    float s0 = 0.f, s1 = 0.f;
#pragma unroll
    for (int c = 0; c < NCLASS; c++) {
        float h = H2p[(size_t)i*64 + c];
        s0 = fmaf(h, a_out[c], s0);
        s1 = fmaf(h, a_out[NCLASS + c], s1);
    }
    src2[i] = s0; dst2[i] = s1;
}

// Final aggregation with INLINE edge weights (no edge_w2 pass):
// w = exp(-leakyrelu(src2[i] + dst2[c])). src2[i] is wave-uniform;
// dst2[c] is a 4-B broadcast gather from a 200 KB L2-resident table.
__global__ __launch_bounds__(256) void agg2(const float* __restrict__ H2p,
                                            const float* __restrict__ src2,
                                            const float* __restrict__ dst2,
                                            const int* __restrict__ row_ptr,
                                            const int* __restrict__ csr_col,
                                            float* __restrict__ out) {
    int wave = (blockIdx.x*256 + threadIdx.x) >> 6;
    int lane = threadIdx.x & 63;
    if (wave >= N_NODES) return;
    int start = row_ptr[wave], end = row_ptr[wave+1];
    float s2i = src2[wave];
    int l = lane < NCLASS ? lane : 0;
    float acc = 0.f, den = 0.f;
    int k = start;
    for (; k + 4 <= end; k += 4) {
        int c0 = csr_col[k],   c1 = csr_col[k+1];
        int c2 = csr_col[k+2], c3 = csr_col[k+3];
        float t0 = s2i + dst2[c0], t1 = s2i + dst2[c1];
        float t2 = s2i + dst2[c2], t3 = s2i + dst2[c3];
        float h0 = H2p[(size_t)c0*64 + l];
        float h1 = H2p[(size_t)c1*64 + l];
        float h2 = H2p[(size_t)c2*64 + l];
        float h3 = H2p[(size_t)c3*64 + l];
        t0 = t0 > 0.f ? t0 : ALPHA*t0;  float w0 = __expf(-t0);
        t1 = t1 > 0.f ? t1 : ALPHA*t1;  float w1 = __expf(-t1);
        t2 = t2 > 0.f ? t2 : ALPHA*t2;  float w2 = __expf(-t2);
        t3 = t3 > 0.f ? t3 : ALPHA*t3;  float w3 = __expf(-t3);
        den += (w0 + w1) + (w2 + w3);
        acc = fmaf(w0, h0, acc);
        acc = fmaf(w1, h1, acc);
        acc = fmaf(w2, h2, acc);
        acc = fmaf(w3, h3, acc);
    }
    for (; k < end; ++k) {
        int c = csr_col[k];
        float t = s2i + dst2[c];
        t = t > 0.f ? t : ALPHA*t;
        float w = __expf(-t);
        den += w;
        acc = fmaf(w, H2p[(size_t)c*64 + l], acc);
    }
    if (lane < NCLASS)
        out[(size_t)wave*NCLASS + lane] = acc / (den + EPS_F);
}

// ---------------------------------------------------------------------------
extern "C" void kernel_launch(void* const* d_in, const int* in_sizes, int n_in,
                              void* d_out, int out_size, void* d_ws, size_t ws_size,
                              hipStream_t stream) {
    const float* x       = (const float*)d_in[0];
    const float* W_heads = (const float*)d_in[1];
    const float* a_heads = (const float*)d_in[2];
    const float* W_out   = (const float*)d_in[3];
    const float* a_out   = (const float*)d_in[4];
    const int*   ei      = (const int*)d_in[5];
    const int*   row     = ei;
    const int*   col     = ei + N_EDGES;
    float* out = (float*)d_out;

    char* ws = (char*)d_ws;
    size_t off = 0;
    auto alloc = [&](size_t bytes) {
        char* p = ws + off;
        off = (off + bytes + 255) & ~(size_t)255;
        return p;
    };
    unsigned short* Wrb   = (unsigned short*)alloc((size_t)512*512*2);
    unsigned short* Wob   = (unsigned short*)alloc((size_t)64*512*2);
    unsigned short* H1p   = (unsigned short*)alloc((size_t)N_NODES*HD*2);
    unsigned short* hcatb = (unsigned short*)alloc((size_t)N_NODES*HD*2);
    float* srcdot  = (float*)alloc((size_t)N_NODES*NHEADS*4);
    float* dstdot  = (float*)alloc((size_t)N_NODES*NHEADS*4);
    float* Wcsr    = (float*)alloc((size_t)N_EDGES*NHEADS*4);
    int*   deg     = (int*)alloc((size_t)N_NODES*4);
    int*   row_ptr = (int*)alloc((size_t)(N_NODES+1)*4);
    int*   cursor  = (int*)alloc((size_t)N_NODES*4);
    int*   ctot    = (int*)alloc(256*4);
    int*   coff    = (int*)alloc(256*4);
    int*   csr_col = (int*)alloc((size_t)N_EDGES*4);
    float* H2p     = (float*)alloc((size_t)N_NODES*64*4);
    float* src2    = (float*)alloc((size_t)N_NODES*4);
    float* dst2    = (float*)alloc((size_t)N_NODES*4);
    (void)ws_size;

    const int EB = (N_EDGES + 255)/256;
    const int WB = (N_NODES*64 + 255)/256;   // wave-per-node grids
    const int NB = (N_NODES + 255)/256;

    // Layer 1
    repackWb<<<(512*512 + 255)/256, 256, 0, stream>>>(W_heads, Wrb, deg);
    repackWout<<<(64*512 + 255)/256, 256, 0, stream>>>(W_out, Wob);
    mfma_gemm1<<<(N_NODES + 127)/128, 512, 0, stream>>>(x, Wrb, H1p, N_NODES);
    dots1<<<WB, 256, 0, stream>>>(H1p, a_heads, srcdot, dstdot);

    // CSR build + fused layer-1 edge weights
    histk<<<EB, 256, 0, stream>>>(row, deg);
    scanA<<<NCHUNK, 256, 0, stream>>>(deg, row_ptr, ctot);
    scanB<<<1, 256, 0, stream>>>(ctot, coff, row_ptr);
    scanC<<<NCHUNK, 256, 0, stream>>>(coff, row_ptr, cursor);
    fillk_w1<<<EB, 256, 0, stream>>>(row, col, srcdot, dstdot, cursor,
                                     csr_col, Wcsr);

    agg1<<<WB, 256, 0, stream>>>(H1p, Wcsr, row_ptr, csr_col, hcatb);

    // Layer 2
    mfma_gemm2<<<(N_NODES + 255)/256, 256, 0, stream>>>(hcatb, Wob, H2p, N_NODES);
    dots2<<<NB, 256, 0, stream>>>(H2p, a_out, src2, dst2);
    agg2<<<WB, 256, 0, stream>>>(H2p, src2, dst2, row_ptr, csr_col, out);
}

// Round 8
// 553.750 us; speedup vs baseline: 1.0143x; 1.0143x over previous
//
#include <hip/hip_runtime.h>
#include <hip/hip_bf16.h>

#define N_NODES 50000
#define N_EDGES 800000
#define NFEAT   512
#define NHID    64
#define NHEADS  8
#define NCLASS  40
#define HD      (NHEADS*NHID)   // 512
#define ALPHA   0.2f
#define EPS_F   1e-16f
#define NCHUNK  ((N_NODES + 255)/256)   // 196

typedef __attribute__((ext_vector_type(8))) short short8;
typedef __attribute__((ext_vector_type(4))) float floatx4;

__device__ __forceinline__ float bf2f(unsigned short u) {
    union { unsigned int i; float f; } v; v.i = ((unsigned int)u) << 16; return v.f;
}
__device__ __forceinline__ unsigned short f2bf(float f) {
    union { __hip_bfloat16 h; unsigned short u; } cv;
    cv.h = __float2bfloat16(f);
    return cv.u;
}

// ---------------------------------------------------------------------------
// Fused prep: repack W_heads -> Wrb (B^T bf16), W_out -> Wob (padded B^T bf16),
// zero deg. One launch instead of three.
__global__ void prep(const float* __restrict__ Wh, unsigned short* __restrict__ Wrb,
                     const float* __restrict__ Wo, unsigned short* __restrict__ Wob,
                     int* __restrict__ deg) {
    int idx = blockIdx.x*256 + threadIdx.x;      // < 512*512
    if (idx >= 512*512) return;
    if (idx < N_NODES) deg[idx] = 0;
    {
        int n = idx >> 9, k = idx & 511;
        int hd = n >> 6, d = n & 63;
        Wrb[idx] = f2bf(Wh[(size_t)hd*NFEAT*NHID + (size_t)k*NHID + d]);
    }
    if (idx < 64*512) {
        int n = idx >> 9, k = idx & 511;
        float v = (n < NCLASS) ? Wo[(size_t)k*NCLASS + n] : 0.f;
        Wob[idx] = f2bf(v);
    }
}

// ---------------------------------------------------------------------------
// Layer-1 MFMA GEMM. 256 threads, 128x128 tile, XCD swizzle, fused fp32->bf16
// A staging, REGISTER-PREFETCH pipeline: global loads for tile k+1 are issued
// right after the LDS-ready barrier of tile k and consumed at the next
// iteration's ds_write, so HBM latency overlaps the MFMA phase.
// Output permuted: H1p[row*512 + d*8 + hd] (col c = hd*64+d).
__global__ __launch_bounds__(256) void mfma_gemm1(const float* __restrict__ A,
                                                  const unsigned short* __restrict__ Bbf,
                                                  unsigned short* __restrict__ H1p, int M) {
    int id = blockIdx.x;
    int rb = (id >> 5)*8 + (id & 7);     // row tile (XCD swizzle: 4 col-tiles of
    int cb = (id >> 3) & 3;              // a row-tile share id%8 -> same XCD)
    int row0 = rb * 128, col0 = cb * 128;
    if (row0 >= M) return;

    __shared__ short Asl[128*40];
    __shared__ short Bsl[128*40];
    int tid  = threadIdx.x;
    int wid  = tid >> 6, lane = tid & 63;
    int lrow = lane & 15, quad = lane >> 4;
    int wm = wid & 1, wn = wid >> 1;

    // staging coords (2 chunks of 8 elems per thread, covering 128 rows x 32 k)
    int sr[2], sk[2];
#pragma unroll
    for (int it = 0; it < 2; ++it) {
        int q = tid + it*256;
        sr[it] = q >> 2; sk[it] = (q & 3) * 8;
    }
    int arow[2];
#pragma unroll
    for (int it = 0; it < 2; ++it) {
        int ar = row0 + sr[it];
        arow[it] = ar < M ? ar : M - 1;
    }

    floatx4 acc[4][4];
#pragma unroll
    for (int mm = 0; mm < 4; mm++)
#pragma unroll
        for (int nn = 0; nn < 4; nn++) acc[mm][nn] = (floatx4){0.f,0.f,0.f,0.f};

    // prefetch registers for tile k0
    float4 fa[2][2];
    short8 fb[2];
#pragma unroll
    for (int it = 0; it < 2; ++it) {
        const float* src = A + (size_t)arow[it]*512 + sk[it];
        fa[it][0] = *(const float4*)src;
        fa[it][1] = *(const float4*)(src + 4);
        fb[it] = *(const short8*)(Bbf + (size_t)(col0 + sr[it])*512 + sk[it]);
    }

    for (int k0 = 0; k0 < 512; k0 += 32) {
        // write current prefetched tile to LDS (vmcnt wait lands here)
#pragma unroll
        for (int it = 0; it < 2; ++it) {
            short8 h;
            h[0] = (short)f2bf(fa[it][0].x); h[1] = (short)f2bf(fa[it][0].y);
            h[2] = (short)f2bf(fa[it][0].z); h[3] = (short)f2bf(fa[it][0].w);
            h[4] = (short)f2bf(fa[it][1].x); h[5] = (short)f2bf(fa[it][1].y);
            h[6] = (short)f2bf(fa[it][1].z); h[7] = (short)f2bf(fa[it][1].w);
            *(short8*)(&Asl[sr[it]*40 + sk[it]]) = h;
            *(short8*)(&Bsl[sr[it]*40 + sk[it]]) = fb[it];
        }
        __syncthreads();
        // issue prefetch for next tile NOW — overlaps the MFMA phase below
        if (k0 + 32 < 512) {
            int kn = k0 + 32;
#pragma unroll
            for (int it = 0; it < 2; ++it) {
                const float* src = A + (size_t)arow[it]*512 + kn + sk[it];
                fa[it][0] = *(const float4*)src;
                fa[it][1] = *(const float4*)(src + 4);
                fb[it] = *(const short8*)(Bbf + (size_t)(col0 + sr[it])*512 + kn + sk[it]);
            }
        }
        short8 af[4], bfr[4];
#pragma unroll
        for (int mm = 0; mm < 4; ++mm)
            af[mm] = *(const short8*)(&Asl[(wm*64 + mm*16 + lrow)*40 + quad*8]);
#pragma unroll
        for (int nn = 0; nn < 4; ++nn)
            bfr[nn] = *(const short8*)(&Bsl[(wn*64 + nn*16 + lrow)*40 + quad*8]);
#pragma unroll
        for (int mm = 0; mm < 4; ++mm)
#pragma unroll
            for (int nn = 0; nn < 4; ++nn)
                acc[mm][nn] = __builtin_amdgcn_mfma_f32_16x16x32_bf16(
                    af[mm], bfr[nn], acc[mm][nn], 0, 0, 0);
        __syncthreads();
    }

#pragma unroll
    for (int mm = 0; mm < 4; ++mm) {
        int rbase = row0 + wm*64 + mm*16 + quad*4;
#pragma unroll
        for (int nn = 0; nn < 4; ++nn) {
            int c = col0 + wn*64 + nn*16 + lrow;
            int off = (c & 63)*8 + (c >> 6);     // permuted layout
#pragma unroll
            for (int r = 0; r < 4; ++r) {
                int grow = rbase + r;
                if (grow < M)
                    H1p[(size_t)grow*512 + off] = f2bf(acc[mm][nn][r]);
            }
        }
    }
}

// ---------------------------------------------------------------------------
// Layer-2 MFMA GEMM: H2p[M,64] = hcatb[M,512] @ Woutb^T (cols 40..63 zero).
__global__ __launch_bounds__(256) void mfma_gemm2(const unsigned short* __restrict__ Abf,
                                                  const unsigned short* __restrict__ Bbf,
                                                  float* __restrict__ H2p, int M) {
    __shared__ short Asl[256*40];
    __shared__ short Bsl[64*40];
    int tid  = threadIdx.x;
    int wid  = tid >> 6, lane = tid & 63;
    int lrow = lane & 15, quad = lane >> 4;
    int row0 = blockIdx.x * 256;

    floatx4 acc[4][4];
#pragma unroll
    for (int mm = 0; mm < 4; mm++)
#pragma unroll
        for (int nn = 0; nn < 4; nn++) acc[mm][nn] = (floatx4){0.f,0.f,0.f,0.f};

    for (int k0 = 0; k0 < 512; k0 += 32) {
#pragma unroll
        for (int it = 0; it < 4; ++it) {     // A: 256 rows x 32k = 1024 chunks
            int q  = tid + it*256;
            int r  = q >> 2, kk = (q & 3) * 8;
            int ar = row0 + r; ar = ar < M ? ar : M - 1;
            *(short8*)(&Asl[r*40 + kk]) =
                *(const short8*)(Abf + (size_t)ar*512 + k0 + kk);
        }
        {                                    // B: 64 rows x 32k = 256 chunks
            int r = tid >> 2, kk = (tid & 3) * 8;
            *(short8*)(&Bsl[r*40 + kk]) =
                *(const short8*)(Bbf + (size_t)r*512 + k0 + kk);
        }
        __syncthreads();
        short8 af[4], bfr[4];
#pragma unroll
        for (int mm = 0; mm < 4; ++mm)
            af[mm] = *(const short8*)(&Asl[(wid*64 + mm*16 + lrow)*40 + quad*8]);
#pragma unroll
        for (int nn = 0; nn < 4; ++nn)
            bfr[nn] = *(const short8*)(&Bsl[(nn*16 + lrow)*40 + quad*8]);
#pragma unroll
        for (int mm = 0; mm < 4; ++mm)
#pragma unroll
            for (int nn = 0; nn < 4; ++nn)
                acc[mm][nn] = __builtin_amdgcn_mfma_f32_16x16x32_bf16(
                    af[mm], bfr[nn], acc[mm][nn], 0, 0, 0);
        __syncthreads();
    }

#pragma unroll
    for (int mm = 0; mm < 4; ++mm) {
        int rbase = row0 + wid*64 + mm*16 + quad*4;
#pragma unroll
        for (int nn = 0; nn < 4; ++nn) {
            int c = nn*16 + lrow;
#pragma unroll
            for (int r = 0; r < 4; ++r) {
                int grow = rbase + r;
                if (grow < M)
                    H2p[(size_t)grow*64 + c] = acc[mm][nn][r];
            }
        }
    }
}

// ---------------------------------------------------------------------------
// Attention dots from PERMUTED H1p. One wave per node; lane = feature d.
__global__ __launch_bounds__(256) void dots1(const unsigned short* __restrict__ H1p,
                                             const float* __restrict__ a_heads,
                                             float* __restrict__ srcdot,
                                             float* __restrict__ dstdot) {
    int wave = (blockIdx.x*256 + threadIdx.x) >> 6;
    int lane = threadIdx.x & 63;
    if (wave >= N_NODES) return;
    short8 hv = *(const short8*)(H1p + (size_t)wave*512 + lane*8);
    float s0[8], s1[8];
#pragma unroll
    for (int j = 0; j < 8; j++) {
        float h = bf2f((unsigned short)hv[j]);
        s0[j] = h * a_heads[j*128 + lane];
        s1[j] = h * a_heads[j*128 + 64 + lane];
    }
#pragma unroll
    for (int off = 32; off > 0; off >>= 1) {
#pragma unroll
        for (int j = 0; j < 8; j++) {
            s0[j] += __shfl_down(s0[j], off, 64);
            s1[j] += __shfl_down(s1[j], off, 64);
        }
    }
    if (lane == 0) {
#pragma unroll
        for (int j = 0; j < 8; j++) {
            srcdot[wave*8 + j] = s0[j];
            dstdot[wave*8 + j] = s1[j];
        }
    }
}

// ---------------------------------------------------------------------------
// CSR build
__global__ void histk(const int* __restrict__ row, int* __restrict__ deg) {
    int e = blockIdx.x*256 + threadIdx.x;
    if (e < N_EDGES) atomicAdd(&deg[row[e]], 1);
}
__global__ void scanA(const int* __restrict__ deg, int* __restrict__ row_ptr,
                      int* __restrict__ chunk_tot) {
    __shared__ int s[256];
    int t = threadIdx.x;
    int idx = blockIdx.x*256 + t;
    int v = (idx < N_NODES) ? deg[idx] : 0;
    s[t] = v;
    __syncthreads();
#pragma unroll
    for (int off = 1; off < 256; off <<= 1) {
        int x = (t >= off) ? s[t-off] : 0;
        __syncthreads();
        s[t] += x;
        __syncthreads();
    }
    if (idx < N_NODES) row_ptr[idx] = s[t] - v;
    if (t == 255) chunk_tot[blockIdx.x] = s[t];
}
__global__ void scanB(const int* __restrict__ chunk_tot, int* __restrict__ chunk_off,
                      int* __restrict__ row_ptr) {
    __shared__ int s[256];
    int t = threadIdx.x;
    int v = (t < NCHUNK) ? chunk_tot[t] : 0;
    s[t] = v;
    __syncthreads();
#pragma unroll
    for (int off = 1; off < 256; off <<= 1) {
        int x = (t >= off) ? s[t-off] : 0;
        __syncthreads();
        s[t] += x;
        __syncthreads();
    }
    if (t < NCHUNK) chunk_off[t] = s[t] - v;
    if (t == 255) row_ptr[N_NODES] = s[t];
}
__global__ void scanC(const int* __restrict__ chunk_off, int* __restrict__ row_ptr,
                      int* __restrict__ cursor) {
    int idx = blockIdx.x*256 + threadIdx.x;
    if (idx < N_NODES) {
        int rp = row_ptr[idx] + chunk_off[idx >> 8];
        row_ptr[idx] = rp;
        cursor[idx] = rp;
    }
}

// Fused CSR fill + layer-1 edge weights, stored in CSR slot order.
__global__ void fillk_w1(const int* __restrict__ row, const int* __restrict__ col,
                         const float* __restrict__ srcdot, const float* __restrict__ dstdot,
                         int* __restrict__ cursor, int* __restrict__ csr_col,
                         float* __restrict__ Wcsr) {
    int e = blockIdx.x*256 + threadIdx.x;
    if (e >= N_EDGES) return;
    int r = row[e], c = col[e];
    int pos = atomicAdd(&cursor[r], 1);
    csr_col[pos] = c;
    float4 sa = *(const float4*)(srcdot + (size_t)r*8);
    float4 sb = *(const float4*)(srcdot + (size_t)r*8 + 4);
    float4 da = *(const float4*)(dstdot + (size_t)c*8);
    float4 db = *(const float4*)(dstdot + (size_t)c*8 + 4);
    float s[8] = {sa.x+da.x, sa.y+da.y, sa.z+da.z, sa.w+da.w,
                  sb.x+db.x, sb.y+db.y, sb.z+db.z, sb.w+db.w};
    float o[8];
#pragma unroll
    for (int j = 0; j < 8; j++) {
        float lr = s[j] > 0.f ? s[j] : ALPHA*s[j];
        o[j] = __expf(-lr);
    }
    *(float4*)(Wcsr + (size_t)pos*8)     = make_float4(o[0], o[1], o[2], o[3]);
    *(float4*)(Wcsr + (size_t)pos*8 + 4) = make_float4(o[4], o[5], o[6], o[7]);
}

// ---------------------------------------------------------------------------
// Layer-1 aggregation + ELU. Wave per node; ONE 16-B gather per edge per lane;
// 4-edge unroll keeps 4 gathers in flight.
__global__ __launch_bounds__(256) void agg1(const unsigned short* __restrict__ H1p,
                                            const float* __restrict__ Wcsr,
                                            const int* __restrict__ row_ptr,
                                            const int* __restrict__ csr_col,
                                            unsigned short* __restrict__ hcatb) {
    int wave = (blockIdx.x*256 + threadIdx.x) >> 6;
    int lane = threadIdx.x & 63;
    if (wave >= N_NODES) return;
    int start = row_ptr[wave], end = row_ptr[wave+1];
    float acc[8], den[8];
#pragma unroll
    for (int j = 0; j < 8; j++) { acc[j] = 0.f; den[j] = 0.f; }

    int k = start;
    for (; k + 4 <= end; k += 4) {
        int c0 = csr_col[k],   c1 = csr_col[k+1];
        int c2 = csr_col[k+2], c3 = csr_col[k+3];
        short8 hv0 = *(const short8*)(H1p + (size_t)c0*512 + lane*8);
        short8 hv1 = *(const short8*)(H1p + (size_t)c1*512 + lane*8);
        short8 hv2 = *(const short8*)(H1p + (size_t)c2*512 + lane*8);
        short8 hv3 = *(const short8*)(H1p + (size_t)c3*512 + lane*8);
        float4 wv[8];
#pragma unroll
        for (int q = 0; q < 8; q++)
            wv[q] = *(const float4*)(Wcsr + (size_t)k*8 + q*4);
        const float* w0 = (const float*)&wv[0];
        const float* w1 = (const float*)&wv[2];
        const float* w2 = (const float*)&wv[4];
        const float* w3 = (const float*)&wv[6];
#pragma unroll
        for (int j = 0; j < 8; j++) {
            den[j] += (w0[j] + w1[j]) + (w2[j] + w3[j]);
            acc[j] = fmaf(w0[j], bf2f((unsigned short)hv0[j]), acc[j]);
            acc[j] = fmaf(w1[j], bf2f((unsigned short)hv1[j]), acc[j]);
            acc[j] = fmaf(w2[j], bf2f((unsigned short)hv2[j]), acc[j]);
            acc[j] = fmaf(w3[j], bf2f((unsigned short)hv3[j]), acc[j]);
        }
    }
    for (; k < end; ++k) {
        int c = csr_col[k];
        float4 wa = *(const float4*)(Wcsr + (size_t)k*8);
        float4 wb = *(const float4*)(Wcsr + (size_t)k*8 + 4);
        short8 hv = *(const short8*)(H1p + (size_t)c*512 + lane*8);
        float w[8] = {wa.x, wa.y, wa.z, wa.w, wb.x, wb.y, wb.z, wb.w};
#pragma unroll
        for (int j = 0; j < 8; j++) {
            den[j] += w[j];
            acc[j] = fmaf(w[j], bf2f((unsigned short)hv[j]), acc[j]);
        }
    }
#pragma unroll
    for (int j = 0; j < 8; j++) {
        float o = acc[j] / (den[j] + EPS_F);
        o = o > 0.f ? o : (__expf(o) - 1.f);   // ELU
        hcatb[(size_t)wave*HD + j*64 + lane] = f2bf(o);
    }
}

// ---------------------------------------------------------------------------
__global__ void dots2(const float* __restrict__ H2p, const float* __restrict__ a_out,
                      float* __restrict__ src2, float* __restrict__ dst2) {
    int i = blockIdx.x*256 + threadIdx.x;
    if (i >= N_NODES) return;
    float s0 = 0.f, s1 = 0.f;
#pragma unroll
    for (int c = 0; c < NCLASS; c++) {
        float h = H2p[(size_t)i*64 + c];
        s0 = fmaf(h, a_out[c], s0);
        s1 = fmaf(h, a_out[NCLASS + c], s1);
    }
    src2[i] = s0; dst2[i] = s1;
}

// Final aggregation with inline edge weights.
__global__ __launch_bounds__(256) void agg2(const float* __restrict__ H2p,
                                            const float* __restrict__ src2,
                                            const float* __restrict__ dst2,
                                            const int* __restrict__ row_ptr,
                                            const int* __restrict__ csr_col,
                                            float* __restrict__ out) {
    int wave = (blockIdx.x*256 + threadIdx.x) >> 6;
    int lane = threadIdx.x & 63;
    if (wave >= N_NODES) return;
    int start = row_ptr[wave], end = row_ptr[wave+1];
    float s2i = src2[wave];
    int l = lane < NCLASS ? lane : 0;
    float acc = 0.f, den = 0.f;
    int k = start;
    for (; k + 4 <= end; k += 4) {
        int c0 = csr_col[k],   c1 = csr_col[k+1];
        int c2 = csr_col[k+2], c3 = csr_col[k+3];
        float t0 = s2i + dst2[c0], t1 = s2i + dst2[c1];
        float t2 = s2i + dst2[c2], t3 = s2i + dst2[c3];
        float h0 = H2p[(size_t)c0*64 + l];
        float h1 = H2p[(size_t)c1*64 + l];
        float h2 = H2p[(size_t)c2*64 + l];
        float h3 = H2p[(size_t)c3*64 + l];
        t0 = t0 > 0.f ? t0 : ALPHA*t0;  float w0 = __expf(-t0);
        t1 = t1 > 0.f ? t1 : ALPHA*t1;  float w1 = __expf(-t1);
        t2 = t2 > 0.f ? t2 : ALPHA*t2;  float w2 = __expf(-t2);
        t3 = t3 > 0.f ? t3 : ALPHA*t3;  float w3 = __expf(-t3);
        den += (w0 + w1) + (w2 + w3);
        acc = fmaf(w0, h0, acc);
        acc = fmaf(w1, h1, acc);
        acc = fmaf(w2, h2, acc);
        acc = fmaf(w3, h3, acc);
    }
    for (; k < end; ++k) {
        int c = csr_col[k];
        float t = s2i + dst2[c];
        t = t > 0.f ? t : ALPHA*t;
        float w = __expf(-t);
        den += w;
        acc = fmaf(w, H2p[(size_t)c*64 + l], acc);
    }
    if (lane < NCLASS)
        out[(size_t)wave*NCLASS + lane] = acc / (den + EPS_F);
}

// ---------------------------------------------------------------------------
extern "C" void kernel_launch(void* const* d_in, const int* in_sizes, int n_in,
                              void* d_out, int out_size, void* d_ws, size_t ws_size,
                              hipStream_t stream) {
    const float* x       = (const float*)d_in[0];
    const float* W_heads = (const float*)d_in[1];
    const float* a_heads = (const float*)d_in[2];
    const float* W_out   = (const float*)d_in[3];
    const float* a_out   = (const float*)d_in[4];
    const int*   ei      = (const int*)d_in[5];
    const int*   row     = ei;
    const int*   col     = ei + N_EDGES;
    float* out = (float*)d_out;

    char* ws = (char*)d_ws;
    size_t off = 0;
    auto alloc = [&](size_t bytes) {
        char* p = ws + off;
        off = (off + bytes + 255) & ~(size_t)255;
        return p;
    };
    unsigned short* Wrb   = (unsigned short*)alloc((size_t)512*512*2);
    unsigned short* Wob   = (unsigned short*)alloc((size_t)64*512*2);
    unsigned short* H1p   = (unsigned short*)alloc((size_t)N_NODES*HD*2);
    unsigned short* hcatb = (unsigned short*)alloc((size_t)N_NODES*HD*2);
    float* srcdot  = (float*)alloc((size_t)N_NODES*NHEADS*4);
    float* dstdot  = (float*)alloc((size_t)N_NODES*NHEADS*4);
    float* Wcsr    = (float*)alloc((size_t)N_EDGES*NHEADS*4);
    int*   deg     = (int*)alloc((size_t)N_NODES*4);
    int*   row_ptr = (int*)alloc((size_t)(N_NODES+1)*4);
    int*   cursor  = (int*)alloc((size_t)N_NODES*4);
    int*   ctot    = (int*)alloc(256*4);
    int*   coff    = (int*)alloc(256*4);
    int*   csr_col = (int*)alloc((size_t)N_EDGES*4);
    float* H2p     = (float*)alloc((size_t)N_NODES*64*4);
    float* src2    = (float*)alloc((size_t)N_NODES*4);
    float* dst2    = (float*)alloc((size_t)N_NODES*4);
    (void)ws_size;

    const int EB = (N_EDGES + 255)/256;
    const int WB = (N_NODES*64 + 255)/256;   // wave-per-node grids
    const int NB = (N_NODES + 255)/256;

    // Layer 1
    prep<<<(512*512 + 255)/256, 256, 0, stream>>>(W_heads, Wrb, W_out, Wob, deg);
    {
        int rtiles = (N_NODES + 127)/128;            // 391
        int nblk = ((rtiles + 7)/8) * 32;            // 1568
        mfma_gemm1<<<nblk, 256, 0, stream>>>(x, Wrb, H1p, N_NODES);
    }
    dots1<<<WB, 256, 0, stream>>>(H1p, a_heads, srcdot, dstdot);

    // CSR build + fused layer-1 edge weights
    histk<<<EB, 256, 0, stream>>>(row, deg);
    scanA<<<NCHUNK, 256, 0, stream>>>(deg, row_ptr, ctot);
    scanB<<<1, 256, 0, stream>>>(ctot, coff, row_ptr);
    scanC<<<NCHUNK, 256, 0, stream>>>(coff, row_ptr, cursor);
    fillk_w1<<<EB, 256, 0, stream>>>(row, col, srcdot, dstdot, cursor,
                                     csr_col, Wcsr);

    agg1<<<WB, 256, 0, stream>>>(H1p, Wcsr, row_ptr, csr_col, hcatb);

    // Layer 2
    mfma_gemm2<<<(N_NODES + 255)/256, 256, 0, stream>>>(hcatb, Wob, H2p, N_NODES);
    dots2<<<NB, 256, 0, stream>>>(H2p, a_out, src2, dst2);
    agg2<<<WB, 256, 0, stream>>>(H2p, src2, dst2, row_ptr, csr_col, out);
}